// Round 2
// baseline (27268.549 us; speedup 1.0000x reference)
//
#include <hip/hip_runtime.h>
#include <cstdint>
#include <cstddef>

typedef __attribute__((ext_vector_type(8))) short short8;
typedef __attribute__((ext_vector_type(4))) float floatx4;

constexpr int kSeq = 512;
constexpr int kBatch = 256;
constexpr int kIn = 15;
constexpr int kH = 512;
constexpr int kG = 4 * kH;            // 2048 gate columns, order i,f,g,o
constexpr int kLdsStride = 520;       // 512 + 8 bf16 pad -> even LDS bank spread
constexpr int kLdsStrideX = 40;       // 32 + 8 pad for the x-weight slice
constexpr size_t kShmemBytes = (size_t)128 * kLdsStride * 2;  // 133,120 B (L2 blocks)

__device__ __forceinline__ unsigned short f2bf(float f) {
    union { float f; unsigned u; } v; v.f = f;
    unsigned u = v.u;
    return (unsigned short)((u + 0x7fffu + ((u >> 16) & 1u)) >> 16);
}

__device__ __forceinline__ float sigm(float x) { return 1.0f / (1.0f + __expf(-x)); }
__device__ __forceinline__ float tanh_(float x) { return 1.0f - 2.0f / (1.0f + __expf(2.0f * x)); }

// plain f32 -> bf16
__global__ void k_conv(const float* __restrict__ src, unsigned short* __restrict__ dst, int n) {
    int i = blockIdx.x * blockDim.x + threadIdx.x;
    if (i < n) dst[i] = f2bf(src[i]);
}

// rows of kIn f32 -> rows of 32 bf16, zero padded
__global__ void k_conv_pad(const float* __restrict__ src, unsigned short* __restrict__ dst, int rows) {
    int i = blockIdx.x * blockDim.x + threadIdx.x;
    if (i >= rows * 32) return;
    int r = i >> 5, k = i & 31;
    dst[i] = (k < kIn) ? f2bf(src[r * kIn + k]) : (unsigned short)0;
}

// Persistent kernel: all 513 pipeline phases in one launch.
// Grid 256 blocks x 256 threads, 1 block/CU (LDS-forced).
// group g = blockIdx&3 (4 batch groups of 64 rows, XCD-affine under RR dispatch);
// role = blockIdx>>2: 0..31 = layer-1 (16 hidden units each), 32..63 = layer-2.
__global__ __launch_bounds__(256) void k_persist(
    const unsigned short* __restrict__ whh1b,  // (2048,512) bf16
    const unsigned short* __restrict__ wih1b,  // (2048,32) bf16, cols >=15 zero
    const unsigned short* __restrict__ wih2b,  // (2048,512) bf16
    const unsigned short* __restrict__ whh2b,  // (2048,512) bf16
    const unsigned short* __restrict__ xb,     // (512,256,32) bf16, cols >=15 zero
    const float* __restrict__ bih1, const float* __restrict__ bhh1,
    const float* __restrict__ bih2, const float* __restrict__ bhh2,
    unsigned short* __restrict__ h1b0, unsigned short* __restrict__ h1b1,
    unsigned short* __restrict__ h2b0, unsigned short* __restrict__ h2b1,
    float* __restrict__ c1, float* __restrict__ c2,
    float* __restrict__ h2f,
    unsigned* __restrict__ ctr)                // 4 counters, 256 B apart
{
    extern __shared__ unsigned short lw[];
    const int bid = blockIdx.x;
    const int g = bid & 3;
    const int role = bid >> 2;
    const bool is2 = role >= 32;
    const int j0 = (role & 31) << 4;          // hidden-unit base within layer
    const int tid = (int)threadIdx.x;
    const int wave = tid >> 6;
    const int lane = tid & 63;
    const int lcol = lane & 15;
    const int quad = lane >> 4;
    const int m0 = (g << 6) + wave * 16;      // this wave's 16-row batch strip
    const int arow = m0 + lcol;
    const int koff = quad * 8;

    // ---- stage this block's weight slices into LDS (once) ----
    if (!is2) {
        for (int i = tid; i < 64 * 64; i += 256) {
            int ln = i >> 6, k8 = (i & 63) << 3;
            int n = ((ln >> 4) << 9) + j0 + (ln & 15);   // gate*512 + j0 + unit
            *(short8*)&lw[ln * kLdsStride + k8] =
                *(const short8*)&whh1b[(size_t)n * kH + k8];
        }
        unsigned short* wx = lw + 64 * kLdsStride;
        for (int i = tid; i < 64 * 4; i += 256) {
            int ln = i >> 2, k8 = (i & 3) << 3;
            int n = ((ln >> 4) << 9) + j0 + (ln & 15);
            *(short8*)&wx[ln * kLdsStrideX + k8] =
                *(const short8*)&wih1b[n * 32 + k8];
        }
    } else {
        for (int i = tid; i < 64 * 64; i += 256) {
            int ln = i >> 6, k8 = (i & 63) << 3;
            int n = ((ln >> 4) << 9) + j0 + (ln & 15);
            *(short8*)&lw[ln * kLdsStride + k8] =
                *(const short8*)&wih2b[(size_t)n * kH + k8];
            *(short8*)&lw[(64 + ln) * kLdsStride + k8] =
                *(const short8*)&whh2b[(size_t)n * kH + k8];
        }
    }
    // biases -> registers (gate sums, same for all rows)
    float bsum[4];
#pragma unroll
    for (int gg = 0; gg < 4; ++gg) {
        int n = (gg << 9) + j0 + lcol;
        bsum[gg] = is2 ? (bih2[n] + bhh2[n]) : (bih1[n] + bhh1[n]);
    }
    __syncthreads();

    const unsigned short* lwx = lw + 64 * kLdsStride;
    unsigned* myctr = ctr + g * 64;   // 256-B separated counters

    for (int t = 0; t <= kSeq; ++t) {
        const bool active = is2 ? (t >= 1) : (t < kSeq);
        if (active) {
            const int s = is2 ? (t - 1) : t;
            floatx4 acc[4];
#pragma unroll
            for (int gg = 0; gg < 4; ++gg)
                acc[gg] = (floatx4){bsum[gg], bsum[gg], bsum[gg], bsum[gg]};

            if (!is2) {
                const unsigned short* hprev = (s & 1) ? h1b0 : h1b1;  // h1[s-1]
                const unsigned short* ap = hprev + (size_t)arow * kH + koff;
#pragma unroll
                for (int kk = 0; kk < 16; ++kk) {
                    short8 a = *(const short8*)(ap + kk * 32);
#pragma unroll
                    for (int gg = 0; gg < 4; ++gg) {
                        short8 b = *(const short8*)&lw[(gg * 16 + lcol) * kLdsStride + kk * 32 + koff];
                        acc[gg] = __builtin_amdgcn_mfma_f32_16x16x32_bf16(a, b, acc[gg], 0, 0, 0);
                    }
                }
                {   // x_t contribution (padded K=32)
                    short8 a = *(const short8*)(xb + ((size_t)s * kBatch + arow) * 32 + koff);
#pragma unroll
                    for (int gg = 0; gg < 4; ++gg) {
                        short8 b = *(const short8*)&lwx[(gg * 16 + lcol) * kLdsStrideX + koff];
                        acc[gg] = __builtin_amdgcn_mfma_f32_16x16x32_bf16(a, b, acc[gg], 0, 0, 0);
                    }
                }
            } else {
                const unsigned short* h1s = (s & 1) ? h1b1 : h1b0;  // h1[s]
                const unsigned short* h2p = (s & 1) ? h2b0 : h2b1;  // h2[s-1]
                const unsigned short* ap1 = h1s + (size_t)arow * kH + koff;
                const unsigned short* ap2 = h2p + (size_t)arow * kH + koff;
#pragma unroll
                for (int kk = 0; kk < 16; ++kk) {
                    short8 a = *(const short8*)(ap1 + kk * 32);
#pragma unroll
                    for (int gg = 0; gg < 4; ++gg) {
                        short8 b = *(const short8*)&lw[(gg * 16 + lcol) * kLdsStride + kk * 32 + koff];
                        acc[gg] = __builtin_amdgcn_mfma_f32_16x16x32_bf16(a, b, acc[gg], 0, 0, 0);
                    }
                }
#pragma unroll
                for (int kk = 0; kk < 16; ++kk) {
                    short8 a = *(const short8*)(ap2 + kk * 32);
#pragma unroll
                    for (int gg = 0; gg < 4; ++gg) {
                        short8 b = *(const short8*)&lw[(64 + gg * 16 + lcol) * kLdsStride + kk * 32 + koff];
                        acc[gg] = __builtin_amdgcn_mfma_f32_16x16x32_bf16(a, b, acc[gg], 0, 0, 0);
                    }
                }
            }

            // epilogue: C/D layout row = m0 + quad*4 + r, col = j0 + lcol
            unsigned short* hw = !is2 ? ((s & 1) ? h1b1 : h1b0)
                                      : ((s & 1) ? h2b1 : h2b0);
            float* cc = !is2 ? c1 : c2;
            const int j = j0 + lcol;
#pragma unroll
            for (int r = 0; r < 4; ++r) {
                int m = m0 + quad * 4 + r;
                size_t off = (size_t)m * kH + j;
                float gi = acc[0][r], gf = acc[1][r], ggv = acc[2][r], go = acc[3][r];
                float cold = cc[off];
                float cn = sigm(gf) * cold + sigm(gi) * tanh_(ggv);
                float hn = sigm(go) * tanh_(cn);
                cc[off] = cn;
                hw[off] = f2bf(hn);
                if (is2 && s == kSeq - 1) h2f[off] = hn;
            }
        }

        if (t < kSeq) {   // inter-phase group barrier (skip after final phase)
            __threadfence();       // make this thread's h/c writes agent-visible
            __syncthreads();
            if (tid == 0) {
                __hip_atomic_fetch_add(myctr, 1u, __ATOMIC_RELEASE, __HIP_MEMORY_SCOPE_AGENT);
                const unsigned target = 64u * (unsigned)(t + 1);
                while (__hip_atomic_load(myctr, __ATOMIC_RELAXED, __HIP_MEMORY_SCOPE_AGENT) < target)
                    __builtin_amdgcn_s_sleep(1);
            }
            __syncthreads();
            __threadfence();       // acquire side: invalidate stale cached h
        }
    }
}

// MLP head: out[m] = 2*(relu(relu(h2[m])@fc1_w.T + fc1_b)@fc_w.T + fc_b)
__global__ __launch_bounds__(64) void k_head(
    const float* __restrict__ h2f, const float* __restrict__ fc1w,
    const float* __restrict__ fc1b, const float* __restrict__ fcw,
    const float* __restrict__ fcb, float* __restrict__ out)
{
    int m = blockIdx.x;
    int j = threadIdx.x;  // 0..63 : FC_HID unit
    const float* hr = h2f + (size_t)m * kH;
    const float* wr = fc1w + (size_t)j * kH;
    float sacc = 0.f;
    for (int k = 0; k < kH; ++k) sacc += fmaxf(hr[k], 0.f) * wr[k];
    float rv = fmaxf(sacc + fc1b[j], 0.f) * fcw[j];
#pragma unroll
    for (int off = 32; off >= 1; off >>= 1) rv += __shfl_down(rv, off);
    if (j == 0) out[m] = 2.0f * (rv + fcb[0]);
}

extern "C" void kernel_launch(void* const* d_in, const int* in_sizes, int n_in,
                              void* d_out, int out_size, void* d_ws, size_t ws_size,
                              hipStream_t stream) {
    const float* x    = (const float*)d_in[0];
    const float* Wih1 = (const float*)d_in[1];
    const float* Whh1 = (const float*)d_in[2];
    const float* bih1 = (const float*)d_in[3];
    const float* bhh1 = (const float*)d_in[4];
    const float* Wih2 = (const float*)d_in[5];
    const float* Whh2 = (const float*)d_in[6];
    const float* bih2 = (const float*)d_in[7];
    const float* bhh2 = (const float*)d_in[8];
    const float* fc1w = (const float*)d_in[9];
    const float* fc1b = (const float*)d_in[10];
    const float* fcw  = (const float*)d_in[11];
    const float* fcb  = (const float*)d_in[12];
    float* out = (float*)d_out;

    char* p = (char*)d_ws;
    auto take = [&](size_t bytes) -> char* {
        char* r = p;
        p += (bytes + 255) & ~(size_t)255;
        return r;
    };
    unsigned short* whh1b = (unsigned short*)take((size_t)kG * kH * 2);
    unsigned short* wih2b = (unsigned short*)take((size_t)kG * kH * 2);
    unsigned short* whh2b = (unsigned short*)take((size_t)kG * kH * 2);
    unsigned short* wih1b = (unsigned short*)take((size_t)kG * 32 * 2);
    unsigned short* xb    = (unsigned short*)take((size_t)kSeq * kBatch * 32 * 2);
    char* state = p;
    unsigned short* h1b0 = (unsigned short*)take((size_t)kBatch * kH * 2);
    unsigned short* h1b1 = (unsigned short*)take((size_t)kBatch * kH * 2);
    unsigned short* h2b0 = (unsigned short*)take((size_t)kBatch * kH * 2);
    unsigned short* h2b1 = (unsigned short*)take((size_t)kBatch * kH * 2);
    float* c1 = (float*)take((size_t)kBatch * kH * 4);
    float* c2 = (float*)take((size_t)kBatch * kH * 4);
    size_t state_bytes = (size_t)((char*)c2 + (size_t)kBatch * kH * 4 - state);
    float* h2f = (float*)take((size_t)kBatch * kH * 4);
    unsigned* ctr = (unsigned*)take(4096);

    // zero h/c state + barrier counters (ws is poisoned 0xAA before every launch)
    hipMemsetAsync(state, 0, state_bytes, stream);
    hipMemsetAsync(ctr, 0, 4096, stream);

    // weight/input conversion to bf16 (re-done every call; no persistent state)
    int n = kG * kH;
    k_conv<<<(n + 255) / 256, 256, 0, stream>>>(Whh1, whh1b, n);
    k_conv<<<(n + 255) / 256, 256, 0, stream>>>(Wih2, wih2b, n);
    k_conv<<<(n + 255) / 256, 256, 0, stream>>>(Whh2, whh2b, n);
    k_conv_pad<<<(kG * 32 + 255) / 256, 256, 0, stream>>>(Wih1, wih1b, kG);
    k_conv_pad<<<(kSeq * kBatch * 32 + 255) / 256, 256, 0, stream>>>(x, xb, kSeq * kBatch);

    // persistent pipeline kernel (all 513 phases)
    hipFuncSetAttribute((const void*)k_persist,
                        hipFuncAttributeMaxDynamicSharedMemorySize, (int)kShmemBytes);
    void* args[] = {&whh1b, &wih1b, &wih2b, &whh2b, &xb,
                    (void*)&bih1, (void*)&bhh1, (void*)&bih2, (void*)&bhh2,
                    &h1b0, &h1b1, &h2b0, &h2b1, &c1, &c2, &h2f, &ctr};
    hipError_t e = hipLaunchCooperativeKernel((const void*)k_persist, dim3(256), dim3(256),
                                              args, (unsigned)kShmemBytes, stream);
    if (e != hipSuccess) {
        // fallback: plain launch (256 blocks, 1/CU by LDS, co-resident in practice)
        k_persist<<<256, 256, kShmemBytes, stream>>>(
            whh1b, wih1b, wih2b, whh2b, xb, bih1, bhh1, bih2, bhh2,
            h1b0, h1b1, h2b0, h2b1, c1, c2, h2f, ctr);
    }

    k_head<<<kBatch, 64, 0, stream>>>(h2f, fc1w, fc1b, fcw, fcb, out);
}

// Round 4
// 5536.075 us; speedup vs baseline: 4.9256x; 4.9256x over previous
//
#include <hip/hip_runtime.h>
#include <cstdint>
#include <cstddef>

typedef __attribute__((ext_vector_type(8))) short short8;
typedef __attribute__((ext_vector_type(4))) float floatx4;

constexpr int kSeq = 512;
constexpr int kBatch = 256;
constexpr int kIn = 15;
constexpr int kH = 512;
constexpr int kG = 4 * kH;                    // 2048 gate cols, order i,f,g,o
constexpr size_t kShmemBytes = 131072;        // 128 fragment-sets * 1 KB

__device__ __forceinline__ unsigned short f2bf(float f) {
    union { float f; unsigned u; } v; v.f = f;
    unsigned u = v.u;
    return (unsigned short)((u + 0x7fffu + ((u >> 16) & 1u)) >> 16);
}

__device__ __forceinline__ float sigm(float x) { return 1.0f / (1.0f + __expf(-x)); }
__device__ __forceinline__ float tanh_(float x) { return 1.0f - 2.0f / (1.0f + __expf(2.0f * x)); }

// 16-byte slab chunk via two 8-byte relaxed agent-scope atomic loads
// (compiler emits the correct coherence bits; served at LLC — no fences).
__device__ __forceinline__ short8 ald16(const unsigned short* p) {
    union { unsigned long long q[2]; short8 v; } c;
    c.q[0] = __hip_atomic_load((const unsigned long long*)p,
                               __ATOMIC_RELAXED, __HIP_MEMORY_SCOPE_AGENT);
    c.q[1] = __hip_atomic_load((const unsigned long long*)(p + 4),
                               __ATOMIC_RELAXED, __HIP_MEMORY_SCOPE_AGENT);
    return c.v;
}

__global__ void k_conv(const float* __restrict__ src, unsigned short* __restrict__ dst, int n) {
    int i = blockIdx.x * blockDim.x + threadIdx.x;
    if (i < n) dst[i] = f2bf(src[i]);
}

__global__ void k_conv_pad(const float* __restrict__ src, unsigned short* __restrict__ dst, int rows) {
    int i = blockIdx.x * blockDim.x + threadIdx.x;
    if (i >= rows * 32) return;
    int r = i >> 5, k = i & 31;
    dst[i] = (k < kIn) ? f2bf(src[r * kIn + k]) : (unsigned short)0;
}

// Persistent kernel: all 513 pipeline phases in one launch.
// group g = blockIdx&3 (64 batch rows each); role = blockIdx>>2:
// 0..31 layer-1 (16 hidden units each), 32..63 layer-2.
// Cross-block h traffic: relaxed agent-scope atomics only. c-state in regs.
__global__ __launch_bounds__(256) void k_persist(
    const unsigned short* __restrict__ whh1b,
    const unsigned short* __restrict__ wih1b,
    const unsigned short* __restrict__ wih2b,
    const unsigned short* __restrict__ whh2b,
    const unsigned short* __restrict__ xb,
    const float* __restrict__ bih1, const float* __restrict__ bhh1,
    const float* __restrict__ bih2, const float* __restrict__ bhh2,
    unsigned short* __restrict__ h1b0, unsigned short* __restrict__ h1b1,
    unsigned short* __restrict__ h2b0, unsigned short* __restrict__ h2b1,
    float* __restrict__ h2f,
    unsigned* __restrict__ ctr)
{
    extern __shared__ unsigned short lw[];
    const int bid = blockIdx.x;
    const int g = bid & 3;
    const int role = bid >> 2;
    const bool is2 = role >= 32;
    const int j0 = (role & 31) << 4;
    const int tid = (int)threadIdx.x;
    const int wave = tid >> 6;
    const int lane = tid & 63;
    const int lcol = lane & 15;
    const int quad = lane >> 4;
    const int m0 = (g << 6) + wave * 16;
    const int arow = m0 + lcol;
    const int koff = quad * 8;

    // ---- stage weight slices into LDS, fragment-linear layout ----
    // fragment f at lw[f*512 .. f*512+511]; lane slot = lane*8 elems (16 B).
    // slot (qd,u) holds W[gate*512 + j0 + u][k = kk*32 + qd*8 .. +7].
    if (!is2) {
        for (int i = tid; i < 4096; i += 256) {
            int ln = i >> 6, gg = ln >> 4, u = ln & 15;
            int c = i & 63, kk = c >> 2, qd = c & 3;
            *(short8*)&lw[((gg * 16 + kk) << 9) + ((qd * 16 + u) << 3)] =
                *(const short8*)&whh1b[(size_t)((gg << 9) + j0 + u) * kH + c * 8];
        }
        for (int i = tid; i < 256; i += 256) {
            int ln = i >> 2, gg = ln >> 4, u = ln & 15;
            int qd = i & 3;
            *(short8*)&lw[((64 + gg) << 9) + ((qd * 16 + u) << 3)] =
                *(const short8*)&wih1b[((gg << 9) + j0 + u) * 32 + qd * 8];
        }
    } else {
        for (int i = tid; i < 4096; i += 256) {
            int ln = i >> 6, gg = ln >> 4, u = ln & 15;
            int c = i & 63, kk = c >> 2, qd = c & 3;
            int dst = ((gg * 16 + kk) << 9) + ((qd * 16 + u) << 3);
            size_t src = (size_t)((gg << 9) + j0 + u) * kH + c * 8;
            *(short8*)&lw[dst] = *(const short8*)&wih2b[src];
            *(short8*)&lw[dst + (64 << 9)] = *(const short8*)&whh2b[src];
        }
    }
    float bsum[4];
#pragma unroll
    for (int gg = 0; gg < 4; ++gg) {
        int n = (gg << 9) + j0 + lcol;
        bsum[gg] = is2 ? (bih2[n] + bhh2[n]) : (bih1[n] + bhh1[n]);
    }
    __syncthreads();

    // c-state in registers: this block owns its (m,j) tile for all 512 steps
    float creg[4] = {0.f, 0.f, 0.f, 0.f};
    unsigned* myctr = ctr + g * 64;   // 256-B separated per-group counters

    for (int t = 0; t <= kSeq; ++t) {
        const bool active = is2 ? (t >= 1) : (t < kSeq);
        if (active) {
            const int s = is2 ? (t - 1) : t;
            floatx4 acc[4];
#pragma unroll
            for (int gg = 0; gg < 4; ++gg)
                acc[gg] = (floatx4){bsum[gg], bsum[gg], bsum[gg], bsum[gg]};

            if (!is2) {
                const unsigned short* hprev = (s & 1) ? h1b0 : h1b1;   // h1[s-1]
                const unsigned short* hp = hprev + (size_t)arow * kH + koff;
                short8 a[16];
#pragma unroll
                for (int kk = 0; kk < 16; ++kk) a[kk] = ald16(hp + kk * 32);
#pragma unroll
                for (int kk = 0; kk < 16; ++kk) {
#pragma unroll
                    for (int gg = 0; gg < 4; ++gg) {
                        short8 b = *(const short8*)&lw[((gg * 16 + kk) << 9) + (lane << 3)];
                        acc[gg] = __builtin_amdgcn_mfma_f32_16x16x32_bf16(a[kk], b, acc[gg], 0, 0, 0);
                    }
                }
                {   // x_t contribution (padded K=32; xb is kernel-boundary coherent)
                    short8 ax = *(const short8*)(xb + ((size_t)s * kBatch + arow) * 32 + koff);
#pragma unroll
                    for (int gg = 0; gg < 4; ++gg) {
                        short8 b = *(const short8*)&lw[((64 + gg) << 9) + (lane << 3)];
                        acc[gg] = __builtin_amdgcn_mfma_f32_16x16x32_bf16(ax, b, acc[gg], 0, 0, 0);
                    }
                }
            } else {
                const unsigned short* h1s = (s & 1) ? h1b1 : h1b0;     // h1[s]
                const unsigned short* h2p = (s & 1) ? h2b0 : h2b1;     // h2[s-1]
                const unsigned short* hp1 = h1s + (size_t)arow * kH + koff;
                const unsigned short* hp2 = h2p + (size_t)arow * kH + koff;
                short8 a[16];
#pragma unroll
                for (int kk = 0; kk < 16; ++kk) a[kk] = ald16(hp1 + kk * 32);
#pragma unroll
                for (int kk = 0; kk < 16; ++kk) {
#pragma unroll
                    for (int gg = 0; gg < 4; ++gg) {
                        short8 b = *(const short8*)&lw[((gg * 16 + kk) << 9) + (lane << 3)];
                        acc[gg] = __builtin_amdgcn_mfma_f32_16x16x32_bf16(a[kk], b, acc[gg], 0, 0, 0);
                    }
                }
#pragma unroll
                for (int kk = 0; kk < 16; ++kk) a[kk] = ald16(hp2 + kk * 32);
#pragma unroll
                for (int kk = 0; kk < 16; ++kk) {
#pragma unroll
                    for (int gg = 0; gg < 4; ++gg) {
                        short8 b = *(const short8*)&lw[((64 + gg * 16 + kk) << 9) + (lane << 3)];
                        acc[gg] = __builtin_amdgcn_mfma_f32_16x16x32_bf16(a[kk], b, acc[gg], 0, 0, 0);
                    }
                }
            }

            // epilogue: C/D row = m0 + quad*4 + r, col = j0 + lcol
            unsigned short* hw = !is2 ? ((s & 1) ? h1b1 : h1b0)
                                      : ((s & 1) ? h2b1 : h2b0);
            const int j = j0 + lcol;
#pragma unroll
            for (int r = 0; r < 4; ++r) {
                int m = m0 + quad * 4 + r;
                size_t off = (size_t)m * kH + j;
                float gi = acc[0][r], gf = acc[1][r], ggv = acc[2][r], go = acc[3][r];
                float cn = sigm(gf) * creg[r] + sigm(gi) * tanh_(ggv);
                float hn = sigm(go) * tanh_(cn);
                creg[r] = cn;
                __hip_atomic_store(&hw[off], f2bf(hn),
                                   __ATOMIC_RELAXED, __HIP_MEMORY_SCOPE_AGENT);
                if (is2 && s == kSeq - 1) h2f[off] = hn;
            }
        }

        if (t < kSeq) {
            // drain my h-stores to the coherence point, then group barrier
            __builtin_amdgcn_s_waitcnt(0);   // vmcnt(0) lgkmcnt(0) expcnt(0)
            __syncthreads();                 // also drains all waves' vmcnt
            if (tid == 0) {
                __hip_atomic_fetch_add(myctr, 1u, __ATOMIC_RELAXED, __HIP_MEMORY_SCOPE_AGENT);
                const unsigned target = 64u * (unsigned)(t + 1);
                while (__hip_atomic_load(myctr, __ATOMIC_RELAXED, __HIP_MEMORY_SCOPE_AGENT) < target)
                    __builtin_amdgcn_s_sleep(2);
            }
            __syncthreads();
        }
    }
}

__global__ __launch_bounds__(64) void k_head(
    const float* __restrict__ h2f, const float* __restrict__ fc1w,
    const float* __restrict__ fc1b, const float* __restrict__ fcw,
    const float* __restrict__ fcb, float* __restrict__ out)
{
    int m = blockIdx.x;
    int j = threadIdx.x;
    const float* hr = h2f + (size_t)m * kH;
    const float* wr = fc1w + (size_t)j * kH;
    float sacc = 0.f;
    for (int k = 0; k < kH; ++k) sacc += fmaxf(hr[k], 0.f) * wr[k];
    float rv = fmaxf(sacc + fc1b[j], 0.f) * fcw[j];
#pragma unroll
    for (int off = 32; off >= 1; off >>= 1) rv += __shfl_down(rv, off);
    if (j == 0) out[m] = 2.0f * (rv + fcb[0]);
}

extern "C" void kernel_launch(void* const* d_in, const int* in_sizes, int n_in,
                              void* d_out, int out_size, void* d_ws, size_t ws_size,
                              hipStream_t stream) {
    const float* x    = (const float*)d_in[0];
    const float* Wih1 = (const float*)d_in[1];
    const float* Whh1 = (const float*)d_in[2];
    const float* bih1 = (const float*)d_in[3];
    const float* bhh1 = (const float*)d_in[4];
    const float* Wih2 = (const float*)d_in[5];
    const float* Whh2 = (const float*)d_in[6];
    const float* bih2 = (const float*)d_in[7];
    const float* bhh2 = (const float*)d_in[8];
    const float* fc1w = (const float*)d_in[9];
    const float* fc1b = (const float*)d_in[10];
    const float* fcw  = (const float*)d_in[11];
    const float* fcb  = (const float*)d_in[12];
    float* out = (float*)d_out;

    char* p = (char*)d_ws;
    auto take = [&](size_t bytes) -> char* {
        char* r = p;
        p += (bytes + 255) & ~(size_t)255;
        return r;
    };
    unsigned short* whh1b = (unsigned short*)take((size_t)kG * kH * 2);
    unsigned short* wih2b = (unsigned short*)take((size_t)kG * kH * 2);
    unsigned short* whh2b = (unsigned short*)take((size_t)kG * kH * 2);
    unsigned short* wih1b = (unsigned short*)take((size_t)kG * 32 * 2);
    unsigned short* xb    = (unsigned short*)take((size_t)kSeq * kBatch * 32 * 2);
    char* state = p;
    unsigned short* h1b0 = (unsigned short*)take((size_t)kBatch * kH * 2);
    unsigned short* h1b1 = (unsigned short*)take((size_t)kBatch * kH * 2);
    unsigned short* h2b0 = (unsigned short*)take((size_t)kBatch * kH * 2);
    unsigned short* h2b1 = (unsigned short*)take((size_t)kBatch * kH * 2);
    size_t state_bytes = (size_t)((char*)h2b1 + (size_t)kBatch * kH * 2 - state);
    float* h2f = (float*)take((size_t)kBatch * kH * 4);
    unsigned* ctr = (unsigned*)take(4096);

    hipMemsetAsync(state, 0, state_bytes, stream);
    hipMemsetAsync(ctr, 0, 4096, stream);

    int n = kG * kH;
    k_conv<<<(n + 255) / 256, 256, 0, stream>>>(Whh1, whh1b, n);
    k_conv<<<(n + 255) / 256, 256, 0, stream>>>(Wih2, wih2b, n);
    k_conv<<<(n + 255) / 256, 256, 0, stream>>>(Whh2, whh2b, n);
    k_conv_pad<<<(kG * 32 + 255) / 256, 256, 0, stream>>>(Wih1, wih1b, kG);
    k_conv_pad<<<(kSeq * kBatch * 32 + 255) / 256, 256, 0, stream>>>(x, xb, kSeq * kBatch);

    hipFuncSetAttribute((const void*)k_persist,
                        hipFuncAttributeMaxDynamicSharedMemorySize, (int)kShmemBytes);
    void* args[] = {&whh1b, &wih1b, &wih2b, &whh2b, &xb,
                    (void*)&bih1, (void*)&bhh1, (void*)&bih2, (void*)&bhh2,
                    &h1b0, &h1b1, &h2b0, &h2b1, &h2f, &ctr};
    hipError_t e = hipLaunchCooperativeKernel((const void*)k_persist, dim3(256), dim3(256),
                                              args, (unsigned)kShmemBytes, stream);
    if (e != hipSuccess) {
        k_persist<<<256, 256, kShmemBytes, stream>>>(
            whh1b, wih1b, wih2b, whh2b, xb, bih1, bhh1, bih2, bhh2,
            h1b0, h1b1, h2b0, h2b1, h2f, ctr);
    }

    k_head<<<kBatch, 64, 0, stream>>>(h2f, fc1w, fc1b, fcw, fcb, out);
}